// Round 14
// baseline (1198.663 us; speedup 1.0000x reference)
//
#include <hip/hip_runtime.h>
#include <hip/hip_fp16.h>
#include <cstdint>

#define DI __device__ __forceinline__

typedef __attribute__((ext_vector_type(8))) _Float16 hx8;     // 8 x fp16 (4 VGPR)
typedef __attribute__((ext_vector_type(16))) float f32x16;    // MFMA 32x32 acc
typedef __attribute__((ext_vector_type(4))) float f4;
typedef unsigned short u16;
typedef unsigned int u32;
typedef unsigned long long u64;
typedef __attribute__((ext_vector_type(4))) u32 u32x4;

// ---------------- problem constants ----------------
constexpr int NB = 1024;
constexpr int NN = 196;
constexpr int NC = 384;
constexpr int NH = 12;
constexpr int HD = 32;
constexpr int C3 = 3 * NC;        // 1152
constexpr int PH = NN * HD;       // 6272 (q per head, u16)
constexpr int KP = 208;           // kT/vT padded n-pitch (u16): 196 + 12 zeros
constexpr int HP = 32 * KP;       // 6656 u16 per head for kT/vT/y buffers
constexpr int NHEADS = NB * NH;   // 12288

// ======== workspace layout (bytes) ========
constexpr size_t SZ_Q    = (size_t)NHEADS * PH * 2;   // 154,140,672 (q fp16)
constexpr size_t SZ_TP   = (size_t)NHEADS * HP * 2;   // 163,577,856 (padded u16 tensor)
constexpr size_t OFF_Q   = 0;
constexpr size_t OFF_K   = SZ_Q;                      // kT fp16 ; y fp16 overlays
constexpr size_t OFF_V   = OFF_K + SZ_TP;             // vT fp16
constexpr size_t OFF_WQF = OFF_V + SZ_TP;             // qkv_w fp16
constexpr size_t SZ_WQ   = (size_t)C3 * NC * 2;
constexpr size_t OFF_WPF = OFF_WQF + SZ_WQ;           // proj_w fp16
constexpr size_t SZ_WP   = (size_t)NC * NC * 2;
constexpr size_t OFF_XF  = OFF_WPF + SZ_WP;           // x fp16

DI void gload_lds16(const void* g, void* l) {
  using GP = const void __attribute__((address_space(1)))*;
  using LP = void __attribute__((address_space(3)))*;
  __builtin_amdgcn_global_load_lds((GP)g, (LP)l, 16, 0, 0);
}

DI float h2f(u16 v)  { _Float16 h = __builtin_bit_cast(_Float16, v); return (float)h; }
DI u16   f2h(float f){ _Float16 h = (_Float16)f; return __builtin_bit_cast(u16, h); }

// ---------------- weights -> fp16 ; zero kT/vT global row-pads ----------------
__global__ void split_weights(const float* __restrict__ qw, const float* __restrict__ pw,
                              u16* __restrict__ qf, u16* __restrict__ pf,
                              u16* ktg, u16* vtg)
{
  int i = blockIdx.x * 256 + threadIdx.x;           // grid 1728*256 = 442,368 = C3*NC
  if (i < C3 * NC) qf[i] = f2h(qw[i]);
  if (i < NC * NC) pf[i] = f2h(pw[i]);
  // zero pads: per head, per row c: n = 196..207 (12 u16 = 3 u64). 12288*64 tails.
  for (u32 t = (u32)i; t < 786432u; t += 442368u) {
    u32 head = t >> 6; int r = t & 63;
    u16* p = ((r & 32) ? vtg : ktg) + (size_t)head * HP + (size_t)(r & 31) * KP + 196;
    *(u64*)(p) = 0; *(u64*)(p + 4) = 0; *(u64*)(p + 8) = 0;
  }
}

// ---------------- x -> fp16 ----------------
__global__ void cvt_x_f16(const float* __restrict__ x, u16* __restrict__ xf)
{
  size_t i = ((size_t)blockIdx.x * 256 + threadIdx.x) * 8;
  f4 a = *(const f4*)(x + i);
  f4 b = *(const f4*)(x + i + 4);
  u16 o[8];
  o[0]=f2h(a[0]); o[1]=f2h(a[1]); o[2]=f2h(a[2]); o[3]=f2h(a[3]);
  o[4]=f2h(b[0]); o[5]=f2h(b[1]); o[6]=f2h(b[2]); o[7]=f2h(b[3]);
  u32x4 pk;
#pragma unroll
  for (int j = 0; j < 4; ++j) pk[j] = (u32)o[2*j] | ((u32)o[2*j+1] << 16);
  *(u32x4*)(xf + i) = pk;
}

// ---------------- qkv = x @ qkv_w^T + b ; relu/pos ; q row-major, k/v transposed ----------------
// r9 skeleton. Swizzle fixed: slot = c ^ ((row>>1)&3) -> any 16-lane phase covers all
// 8 (half,slot) bank-starts exactly 2x (2-way = free, m136), vs r9's row&3 form whose
// phases had 4 lanes on one bank-start (4-way, the persistent 2.5e7 conflicts).
__global__ __launch_bounds__(256, 5) void qkv_gemm_f16(
    const u16* __restrict__ xf, const u16* __restrict__ wf,
    const float* __restrict__ bias, const float* __restrict__ pos,
    u16* __restrict__ qo, u16* __restrict__ ko, u16* __restrict__ vo)
{
  __shared__ __align__(16) char lds[2][16384];   // A 8K | B 8K ; epilogue: 18KB transpose tile
  const int tid  = threadIdx.x;
  const int lane = tid & 63, wv = tid >> 6;
  const int L  = ((int)blockIdx.x & 7) * 1764 + ((int)blockIdx.x >> 3); // 14112 = 8*1764
  const int rt = L / 9, ct = L - rt * 9;
  const int m0 = rt * 128, t0 = ct * 128;

  const u16* spA[2];
  const u16* spB[2];
#pragma unroll
  for (int j = 0; j < 2; ++j) {
    int g = j * 256 + tid;
    int row = g >> 2, slot = g & 3;
    int c = slot ^ ((row >> 1) & 3);
    spA[j] = xf + (size_t)(m0 + row) * NC + c * 8;
    spB[j] = wf + (size_t)(t0 + row) * NC + c * 8;
  }

  auto stage = [&](char* buf) {
#pragma unroll
    for (int j = 0; j < 2; ++j) {
      gload_lds16(spA[j], buf + (j * 256 + tid) * 16);
      spA[j] += 32;
      gload_lds16(spB[j], buf + 8192 + (j * 256 + tid) * 16);
      spB[j] += 32;
    }
  };

  const int wm = (wv & 1) * 64, wn = (wv >> 1) * 64;
  const int l15 = lane & 15, l4 = lane >> 4;
  const int sl = l4 ^ ((l15 >> 1) & 3);
  int aoff[4], boff[4];
#pragma unroll
  for (int i = 0; i < 4; ++i) {
    aoff[i] = (wm + i * 16 + l15) * 64 + sl * 16;
    boff[i] = 8192 + (wn + i * 16 + l15) * 64 + sl * 16;
  }

  f4 acc[4][4];
  const f4 fz = {0.f, 0.f, 0.f, 0.f};
#pragma unroll
  for (int i = 0; i < 4; ++i)
#pragma unroll
    for (int j = 0; j < 4; ++j) acc[i][j] = fz;

  stage(lds[0]);
  for (int kt = 0; kt < 12; ++kt) {
    __syncthreads();
    if (kt < 11) stage(lds[(kt + 1) & 1]);
    char* buf = lds[kt & 1];
    hx8 af[4], bf4[4];
#pragma unroll
    for (int i = 0; i < 4; ++i) {
      af[i]  = *(const hx8*)(buf + aoff[i]);
      bf4[i] = *(const hx8*)(buf + boff[i]);
    }
#pragma unroll
    for (int mi = 0; mi < 4; ++mi)
#pragma unroll
      for (int ni = 0; ni < 4; ++ni)
        acc[mi][ni] = __builtin_amdgcn_mfma_f32_16x16x32_f16(af[mi], bf4[ni], acc[mi][ni], 0, 0, 0);
  }

  const int s = ct / 3, cb = (ct - s * 3) * 128;   // s: 0=q 1=k 2=v
  float biasv[4];
#pragma unroll
  for (int ni = 0; ni < 4; ++ni) biasv[ni] = bias[t0 + wn + ni * 16 + l15];

  if (s == 0) {
    // q -> [bh][n][32] row-major (direct)
#pragma unroll
    for (int mi = 0; mi < 4; ++mi) {
#pragma unroll
      for (int rr = 0; rr < 4; ++rr) {
        int m = m0 + wm + mi * 16 + l4 * 4 + rr;
        int b = m / 196, n = m - b * 196;
#pragma unroll
        for (int ni = 0; ni < 4; ++ni) {
          int c = cb + wn + ni * 16 + l15;
          float val = acc[mi][ni][rr] + biasv[ni];
          qo[((size_t)b * 12 + (c >> 5)) * PH + (size_t)n * 32 + (c & 31)] = f2h(fmaxf(val, 0.f));
        }
      }
    }
  } else {
    // k/v -> [bh][c][208] via LDS transpose staging (2 passes of 64 m-rows)
    u16* outp = (s == 1) ? ko : vo;
    u16* tb = (u16*)&lds[0][0];                      // [128 c][72 m-pitch] u16 = 18432 B
    __syncthreads();                                 // staging buffers dead
#pragma unroll
    for (int p = 0; p < 2; ++p) {
      if (wm == p * 64) {
#pragma unroll
        for (int mi = 0; mi < 4; ++mi) {
#pragma unroll
          for (int ni = 0; ni < 4; ++ni) {
            int cl = wn + ni * 16 + l15;
            u64 w = 0;
#pragma unroll
            for (int rr = 0; rr < 4; ++rr) {
              int m = m0 + wm + mi * 16 + l4 * 4 + rr;
              int b = m / 196, n = m - b * 196;
              float val = acc[mi][ni][rr] + biasv[ni];
              if (s == 1) val = fmaxf(val + pos[n * 384 + cb + cl], 0.f);
              w |= (u64)f2h(val) << (rr * 16);
            }
            *(u64*)(tb + (size_t)cl * 72 + (mi * 16 + l4 * 4)) = w;
          }
        }
      }
      __syncthreads();
      // read-back: thread -> (row r, half h); 4 x 16B chunks -> coalesced [c][n] writes
      {
        int r = tid >> 1, h = tid & 1;
        int cgl = cb + r, head = cgl >> 5, cc = cgl & 31;
        const u16* src = tb + (size_t)r * 72 + h * 32;
#pragma unroll
        for (int e = 0; e < 4; ++e) {
          u32x4 dd = *(const u32x4*)(src + e * 8);
          int mg = m0 + p * 64 + h * 32 + e * 8;
          int b = mg / 196, n = mg - b * 196;
          if (n <= 188) {
            u16* gp = outp + ((size_t)b * 12 + head) * HP + (size_t)cc * KP + n;
            *(u64*)gp       = ((const u64*)&dd)[0];
            *(u64*)(gp + 4) = ((const u64*)&dd)[1];
          } else {
            const u16* du = (const u16*)&dd;
#pragma unroll
            for (int ee = 0; ee < 8; ++ee) {
              int m2 = mg + ee, b2 = m2 / 196, n2 = m2 - b2 * 196;
              outp[((size_t)b2 * 12 + head) * HP + (size_t)cc * KP + n2] = du[ee];
            }
          }
        }
      }
      __syncthreads();
    }
  }
}

// ---------------- per-(b,h): kv & out on MFMA ; conv + z on VALU (r9 verbatim) ----------------
__global__ __launch_bounds__(256, 4) void attn_conv(
    const u16* __restrict__ q, const u16* kt, const u16* __restrict__ vt,
    u16* y, const float* __restrict__ dwc_w, const float* __restrict__ dwc_b)
{
  __shared__ __align__(16) char smem[30096];
  u16*   sKT = (u16*)smem;                   // also fmT after bar2
  u16*   sVT = (u16*)(smem + 13312);
  u16*   sKV = (u16*)(smem + 26624);         // kvT fp16 [d][40]
  float* sZ  = (float*)(smem + 29184);       // z[196]
  float* sKS = (float*)(smem + 29968);       // ksum[32]

  const int tid  = threadIdx.x;
  const int lane = tid & 63, wv = tid >> 6;
  const int r31 = lane & 31, hi = lane >> 5;
  const size_t bh = blockIdx.x;
  const u16* qh = q  + bh * PH;
  const u16* kh = kt + bh * HP;
  const u16* vh = vt + bh * HP;
  u16*       yh = y  + bh * HP;

  for (int i = tid; i < 832; i += 256) gload_lds16(kh + i * 8, smem + i * 16);
  for (int i = tid; i < 832; i += 256) gload_lds16(vh + i * 8, smem + 13312 + i * 16);
  __syncthreads();                                          // bar1

  if (wv == 0) {
    f32x16 kacc = {0,0,0,0,0,0,0,0,0,0,0,0,0,0,0,0};
#pragma unroll
    for (int kk = 0; kk < 13; ++kk) {
      hx8 a = *(const hx8*)(sKT + r31 * KP + kk * 16 + hi * 8);
      hx8 b = *(const hx8*)(sVT + r31 * KP + kk * 16 + hi * 8);
      kacc = __builtin_amdgcn_mfma_f32_32x32x16_f16(a, b, kacc, 0, 0, 0);
    }
#pragma unroll
    for (int r = 0; r < 16; ++r) {
      int cc = (r & 3) + 8 * (r >> 2) + 4 * hi;             // D row = c
      sKV[r31 * 40 + cc] = f2h(kacc[r]);                    // kvT[d=r31][c]
    }
  }

  {
    int c = tid >> 3, ns = tid & 7;
    float s = 0.f;
#pragma unroll
    for (int i = 0; i < 26; ++i) s += h2f(sKT[c * KP + ns * 26 + i]);
#pragma unroll
    for (int off = 1; off <= 4; off <<= 1) s += __shfl_xor(s, off);
    if (ns == 0) sKS[c] = s;
  }
  __syncthreads();                                          // bar2

  if (tid < 196) {
    float pz = 0.f;
#pragma unroll
    for (int g = 0; g < 4; ++g) {
      u32x4 qw = *(const u32x4*)(qh + (size_t)tid * 32 + g * 8);
#pragma unroll
      for (int j = 0; j < 4; ++j) {
        pz += h2f((u16)(qw[j] & 0xffffu)) * sKS[g * 8 + 2 * j]
            + h2f((u16)(qw[j] >> 16))     * sKS[g * 8 + 2 * j + 1];
      }
    }
    sZ[tid] = 1.f / (pz + 1e-6f);
  }

  u16* sFM = sKT;
  auto conv_unit = [&](int u) {
    int d = u & 31, py = u >> 5;
    float fm[14];
    float bv = dwc_b[d];
#pragma unroll
    for (int px = 0; px < 14; ++px) fm[px] = bv;
#pragma unroll
    for (int ky = 0; ky < 5; ++ky) {
      int yy = py + ky - 2;
      if (yy < 0 || yy >= 14) continue;
      float w[5];
#pragma unroll
      for (int t = 0; t < 5; ++t) w[t] = dwc_w[d * 25 + ky * 5 + t];
      float r[14];
      const u32* vrow = (const u32*)(sVT + d * KP + yy * 14);
#pragma unroll
      for (int x2 = 0; x2 < 7; ++x2) {
        u32 pr = vrow[x2];
        r[2 * x2]     = h2f((u16)(pr & 0xffffu));
        r[2 * x2 + 1] = h2f((u16)(pr >> 16));
      }
#pragma unroll
      for (int px = 0; px < 14; ++px) {
#pragma unroll
        for (int kx = 0; kx < 5; ++kx) {
          int xx = px + kx - 2;
          if (xx < 0 || xx > 13) continue;
          fm[px] += w[kx] * r[xx];
        }
      }
    }
#pragma unroll
    for (int px = 0; px < 14; ++px)
      sFM[d * KP + py * 14 + px] = f2h(fm[px]);
  };
  conv_unit(tid);
  if (tid >= 64) conv_unit(tid + 192);
  __syncthreads();                                          // bar3

#pragma unroll
  for (int rep = 0; rep < 2; ++rep) {
    int T = wv + rep * 4;
    if (T >= 7) break;
    const u16* qrow = qh + (size_t)(T * 32 + r31) * 32;
    f32x16 acc = {0,0,0,0,0,0,0,0,0,0,0,0,0,0,0,0};
#pragma unroll
    for (int s = 0; s < 2; ++s) {
      hx8 a = *(const hx8*)(qrow + hi * 8 + s * 16);
      hx8 b = *(const hx8*)(sKV + r31 * 40 + hi * 8 + s * 16);
      acc = __builtin_amdgcn_mfma_f32_32x32x16_f16(a, b, acc, 0, 0, 0);
    }
#pragma unroll
    for (int r = 0; r < 16; ++r) {
      int row = (r & 3) + 8 * (r >> 2) + 4 * hi;
      int n = T * 32 + row;
      if (n < 196) {
        float val = acc[r] * sZ[n] + h2f(sFM[r31 * KP + n]);
        yh[n * 32 + r31] = f2h(val);
      }
    }
  }
}

// ---------------- out = y @ proj_w^T + proj_b (fp16 MFMA) ----------------
__global__ __launch_bounds__(256, 5) void proj_gemm_f16(
    const u16* __restrict__ yf, const u16* __restrict__ wf,
    const float* __restrict__ bias, float* __restrict__ out)
{
  __shared__ __align__(16) char lds[2][16384];   // A 8K | B 8K
  const int tid  = threadIdx.x;
  const int lane = tid & 63, wv = tid >> 6;
  const int L  = ((int)blockIdx.x & 7) * 588 + ((int)blockIdx.x >> 3);  // 4704 = 8*588
  const int rt = L / 3, ct = L - rt * 3;
  const int m0 = rt * 128, t0 = ct * 128;

  const u16* spA[2];
  const u16* spB[2];
#pragma unroll
  for (int j = 0; j < 2; ++j) {
    int g = j * 256 + tid;
    int row = g >> 2, slot = g & 3;
    int c = slot ^ ((row >> 1) & 3);
    int m = m0 + row;
    int b = m / 196, n = m - b * 196;
    spA[j] = yf + (size_t)b * (12 * HP) + (size_t)n * 32 + c * 8;  // += HP per head
    spB[j] = wf + (size_t)(t0 + row) * NC + c * 8;
  }

  auto stage = [&](char* buf) {
#pragma unroll
    for (int j = 0; j < 2; ++j) {
      gload_lds16(spA[j], buf + (j * 256 + tid) * 16);
      spA[j] += HP;
      gload_lds16(spB[j], buf + 8192 + (j * 256 + tid) * 16);
      spB[j] += 32;
    }
  };

  const int wm = (wv & 1) * 64, wn = (wv >> 1) * 64;
  const int l15 = lane & 15, l4 = lane >> 4;
  const int sl = l4 ^ ((l15 >> 1) & 3);
  int aoff[4], boff[4];
#pragma unroll
  for (int i = 0; i < 4; ++i) {
    aoff[i] = (wm + i * 16 + l15) * 64 + sl * 16;
    boff[i] = 8192 + (wn + i * 16 + l15) * 64 + sl * 16;
  }

  f4 acc[4][4];
  const f4 fz = {0.f, 0.f, 0.f, 0.f};
#pragma unroll
  for (int i = 0; i < 4; ++i)
#pragma unroll
    for (int j = 0; j < 4; ++j) acc[i][j] = fz;

  stage(lds[0]);
  for (int kt = 0; kt < 12; ++kt) {
    __syncthreads();
    if (kt < 11) stage(lds[(kt + 1) & 1]);
    char* buf = lds[kt & 1];
    hx8 af[4], bf4[4];
#pragma unroll
    for (int i = 0; i < 4; ++i) {
      af[i]  = *(const hx8*)(buf + aoff[i]);
      bf4[i] = *(const hx8*)(buf + boff[i]);
    }
#pragma unroll
    for (int mi = 0; mi < 4; ++mi)
#pragma unroll
      for (int ni = 0; ni < 4; ++ni)
        acc[mi][ni] = __builtin_amdgcn_mfma_f32_16x16x32_f16(af[mi], bf4[ni], acc[mi][ni], 0, 0, 0);
  }

  float biasv[4];
#pragma unroll
  for (int ni = 0; ni < 4; ++ni) biasv[ni] = bias[t0 + wn + ni * 16 + l15];
#pragma unroll
  for (int mi = 0; mi < 4; ++mi) {
#pragma unroll
    for (int rr = 0; rr < 4; ++rr) {
      int m = m0 + wm + mi * 16 + l4 * 4 + rr;
      size_t ob = (size_t)m * 384 + t0 + wn;
#pragma unroll
      for (int ni = 0; ni < 4; ++ni)
        out[ob + ni * 16 + l15] = acc[mi][ni][rr] + biasv[ni];
    }
  }
}

// ---------------- launcher ----------------
extern "C" void kernel_launch(void* const* d_in, const int* in_sizes, int n_in,
                              void* d_out, int out_size, void* d_ws, size_t ws_size,
                              hipStream_t stream)
{
  const float* x      = (const float*)d_in[0];
  const float* qkv_w  = (const float*)d_in[1];
  const float* qkv_b  = (const float*)d_in[2];
  const float* proj_w = (const float*)d_in[3];
  const float* proj_b = (const float*)d_in[4];
  const float* dwc_w  = (const float*)d_in[5];
  const float* dwc_b  = (const float*)d_in[6];
  const float* pos    = (const float*)d_in[7];
  float* out = (float*)d_out;
  char* ws = (char*)d_ws;

  u16* qb  = (u16*)(ws + OFF_Q);     // q fp16 [bh][n][32]
  u16* kb  = (u16*)(ws + OFF_K);     // kT fp16 [bh][c][208]
  u16* vb  = (u16*)(ws + OFF_V);     // vT fp16 [bh][d][208]
  u16* wqf = (u16*)(ws + OFF_WQF);
  u16* wpf = (u16*)(ws + OFF_WPF);
  u16* xf  = (u16*)(ws + OFF_XF);
  u16* yb  = (u16*)(ws + OFF_K);     // y fp16 [bh][n][32] (head stride HP), overlays kT

  split_weights<<<1728, 256, 0, stream>>>(qkv_w, proj_w, wqf, wpf, kb, vb);
  cvt_x_f16<<<37632, 256, 0, stream>>>(x, xf);
  qkv_gemm_f16<<<14112, 256, 0, stream>>>(xf, wqf, qkv_b, pos, qb, kb, vb);
  attn_conv<<<12288, 256, 0, stream>>>(qb, kb, vb, yb, dwc_w, dwc_b);
  proj_gemm_f16<<<4704, 256, 0, stream>>>(yb, wpf, proj_b, out);
}

// Round 15
// 884.514 us; speedup vs baseline: 1.3552x; 1.3552x over previous
//
#include <hip/hip_runtime.h>
#include <hip/hip_fp16.h>
#include <cstdint>

#define DI __device__ __forceinline__

typedef __attribute__((ext_vector_type(8))) _Float16 hx8;     // 8 x fp16 (4 VGPR)
typedef __attribute__((ext_vector_type(16))) float f32x16;    // MFMA 32x32 acc
typedef __attribute__((ext_vector_type(4))) float f4;
typedef unsigned short u16;
typedef unsigned int u32;
typedef unsigned long long u64;
typedef __attribute__((ext_vector_type(4))) u32 u32x4;

// ---------------- problem constants ----------------
constexpr int NB = 1024;
constexpr int NN = 196;
constexpr int NC = 384;
constexpr int NH = 12;
constexpr int HD = 32;
constexpr int C3 = 3 * NC;        // 1152
constexpr int PH = NN * HD;       // 6272 (q per head, u16)
constexpr int KP = 208;           // kT/vT padded n-pitch (u16): 196 + 12 zeros
constexpr int HP = 32 * KP;       // 6656 u16 per head for kT/vT/y buffers
constexpr int NHEADS = NB * NH;   // 12288

// ======== workspace layout (bytes) ========
constexpr size_t SZ_Q    = (size_t)NHEADS * PH * 2;   // 154,140,672 (q fp16)
constexpr size_t SZ_TP   = (size_t)NHEADS * HP * 2;   // 163,577,856 (padded u16 tensor)
constexpr size_t OFF_Q   = 0;
constexpr size_t OFF_K   = SZ_Q;                      // kT fp16 ; y fp16 overlays
constexpr size_t OFF_V   = OFF_K + SZ_TP;             // vT fp16
constexpr size_t OFF_WQF = OFF_V + SZ_TP;             // qkv_w fp16
constexpr size_t SZ_WQ   = (size_t)C3 * NC * 2;
constexpr size_t OFF_WPF = OFF_WQF + SZ_WQ;           // proj_w fp16
constexpr size_t SZ_WP   = (size_t)NC * NC * 2;
constexpr size_t OFF_XF  = OFF_WPF + SZ_WP;           // x fp16

DI void gload_lds16(const void* g, void* l) {
  using GP = const void __attribute__((address_space(1)))*;
  using LP = void __attribute__((address_space(3)))*;
  __builtin_amdgcn_global_load_lds((GP)g, (LP)l, 16, 0, 0);
}

DI float h2f(u16 v)  { _Float16 h = __builtin_bit_cast(_Float16, v); return (float)h; }
DI u16   f2h(float f){ _Float16 h = (_Float16)f; return __builtin_bit_cast(u16, h); }

// ---------------- weights -> fp16 ; zero kT/vT global row-pads ----------------
__global__ void split_weights(const float* __restrict__ qw, const float* __restrict__ pw,
                              u16* __restrict__ qf, u16* __restrict__ pf,
                              u16* ktg, u16* vtg)
{
  int i = blockIdx.x * 256 + threadIdx.x;           // grid 1728*256 = 442,368 = C3*NC
  if (i < C3 * NC) qf[i] = f2h(qw[i]);
  if (i < NC * NC) pf[i] = f2h(pw[i]);
  // zero pads: per head, per row c: n = 196..207 (12 u16 = 3 u64). 12288*64 tails.
  for (u32 t = (u32)i; t < 786432u; t += 442368u) {
    u32 head = t >> 6; int r = t & 63;
    u16* p = ((r & 32) ? vtg : ktg) + (size_t)head * HP + (size_t)(r & 31) * KP + 196;
    *(u64*)(p) = 0; *(u64*)(p + 4) = 0; *(u64*)(p + 8) = 0;
  }
}

// ---------------- x -> fp16 ----------------
__global__ void cvt_x_f16(const float* __restrict__ x, u16* __restrict__ xf)
{
  size_t i = ((size_t)blockIdx.x * 256 + threadIdx.x) * 8;
  f4 a = *(const f4*)(x + i);
  f4 b = *(const f4*)(x + i + 4);
  u16 o[8];
  o[0]=f2h(a[0]); o[1]=f2h(a[1]); o[2]=f2h(a[2]); o[3]=f2h(a[3]);
  o[4]=f2h(b[0]); o[5]=f2h(b[1]); o[6]=f2h(b[2]); o[7]=f2h(b[3]);
  u32x4 pk;
#pragma unroll
  for (int j = 0; j < 4; ++j) pk[j] = (u32)o[2*j] | ((u32)o[2*j+1] << 16);
  *(u32x4*)(xf + i) = pk;
}

// ---------------- qkv = x @ qkv_w^T + b ; relu/pos ; q row-major, k/v transposed ----------------
// r9 skeleton + conflict-free swizzle slot = c ^ ((row>>1)&3) (r14-verified: conflicts
// 2.5e7 -> 3.6e6). Occupancy bound back to r9's (256,4) — (256,5) spilled (r14: VGPR 48,
// +381MB scratch writes).
__global__ __launch_bounds__(256, 4) void qkv_gemm_f16(
    const u16* __restrict__ xf, const u16* __restrict__ wf,
    const float* __restrict__ bias, const float* __restrict__ pos,
    u16* __restrict__ qo, u16* __restrict__ ko, u16* __restrict__ vo)
{
  __shared__ __align__(16) char lds[2][16384];   // A 8K | B 8K ; epilogue: 18KB transpose tile
  const int tid  = threadIdx.x;
  const int lane = tid & 63, wv = tid >> 6;
  const int L  = ((int)blockIdx.x & 7) * 1764 + ((int)blockIdx.x >> 3); // 14112 = 8*1764
  const int rt = L / 9, ct = L - rt * 9;
  const int m0 = rt * 128, t0 = ct * 128;

  const u16* spA[2];
  const u16* spB[2];
#pragma unroll
  for (int j = 0; j < 2; ++j) {
    int g = j * 256 + tid;
    int row = g >> 2, slot = g & 3;
    int c = slot ^ ((row >> 1) & 3);
    spA[j] = xf + (size_t)(m0 + row) * NC + c * 8;
    spB[j] = wf + (size_t)(t0 + row) * NC + c * 8;
  }

  auto stage = [&](char* buf) {
#pragma unroll
    for (int j = 0; j < 2; ++j) {
      gload_lds16(spA[j], buf + (j * 256 + tid) * 16);
      spA[j] += 32;
      gload_lds16(spB[j], buf + 8192 + (j * 256 + tid) * 16);
      spB[j] += 32;
    }
  };

  const int wm = (wv & 1) * 64, wn = (wv >> 1) * 64;
  const int l15 = lane & 15, l4 = lane >> 4;
  const int sl = l4 ^ ((l15 >> 1) & 3);
  int aoff[4], boff[4];
#pragma unroll
  for (int i = 0; i < 4; ++i) {
    aoff[i] = (wm + i * 16 + l15) * 64 + sl * 16;
    boff[i] = 8192 + (wn + i * 16 + l15) * 64 + sl * 16;
  }

  f4 acc[4][4];
  const f4 fz = {0.f, 0.f, 0.f, 0.f};
#pragma unroll
  for (int i = 0; i < 4; ++i)
#pragma unroll
    for (int j = 0; j < 4; ++j) acc[i][j] = fz;

  stage(lds[0]);
  for (int kt = 0; kt < 12; ++kt) {
    __syncthreads();
    if (kt < 11) stage(lds[(kt + 1) & 1]);
    char* buf = lds[kt & 1];
    hx8 af[4], bf4[4];
#pragma unroll
    for (int i = 0; i < 4; ++i) {
      af[i]  = *(const hx8*)(buf + aoff[i]);
      bf4[i] = *(const hx8*)(buf + boff[i]);
    }
#pragma unroll
    for (int mi = 0; mi < 4; ++mi)
#pragma unroll
      for (int ni = 0; ni < 4; ++ni)
        acc[mi][ni] = __builtin_amdgcn_mfma_f32_16x16x32_f16(af[mi], bf4[ni], acc[mi][ni], 0, 0, 0);
  }

  const int s = ct / 3, cb = (ct - s * 3) * 128;   // s: 0=q 1=k 2=v
  float biasv[4];
#pragma unroll
  for (int ni = 0; ni < 4; ++ni) biasv[ni] = bias[t0 + wn + ni * 16 + l15];

  if (s == 0) {
    // q -> [bh][n][32] row-major (direct)
#pragma unroll
    for (int mi = 0; mi < 4; ++mi) {
#pragma unroll
      for (int rr = 0; rr < 4; ++rr) {
        int m = m0 + wm + mi * 16 + l4 * 4 + rr;
        int b = m / 196, n = m - b * 196;
#pragma unroll
        for (int ni = 0; ni < 4; ++ni) {
          int c = cb + wn + ni * 16 + l15;
          float val = acc[mi][ni][rr] + biasv[ni];
          qo[((size_t)b * 12 + (c >> 5)) * PH + (size_t)n * 32 + (c & 31)] = f2h(fmaxf(val, 0.f));
        }
      }
    }
  } else {
    // k/v -> [bh][c][208] via LDS transpose staging (2 passes of 64 m-rows)
    u16* outp = (s == 1) ? ko : vo;
    u16* tb = (u16*)&lds[0][0];                      // [128 c][72 m-pitch] u16 = 18432 B
    __syncthreads();                                 // staging buffers dead
#pragma unroll
    for (int p = 0; p < 2; ++p) {
      if (wm == p * 64) {
#pragma unroll
        for (int mi = 0; mi < 4; ++mi) {
#pragma unroll
          for (int ni = 0; ni < 4; ++ni) {
            int cl = wn + ni * 16 + l15;
            u64 w = 0;
#pragma unroll
            for (int rr = 0; rr < 4; ++rr) {
              int m = m0 + wm + mi * 16 + l4 * 4 + rr;
              int b = m / 196, n = m - b * 196;
              float val = acc[mi][ni][rr] + biasv[ni];
              if (s == 1) val = fmaxf(val + pos[n * 384 + cb + cl], 0.f);
              w |= (u64)f2h(val) << (rr * 16);
            }
            *(u64*)(tb + (size_t)cl * 72 + (mi * 16 + l4 * 4)) = w;
          }
        }
      }
      __syncthreads();
      // read-back: thread -> (row r, half h); 4 x 16B chunks -> coalesced [c][n] writes
      {
        int r = tid >> 1, h = tid & 1;
        int cgl = cb + r, head = cgl >> 5, cc = cgl & 31;
        const u16* src = tb + (size_t)r * 72 + h * 32;
#pragma unroll
        for (int e = 0; e < 4; ++e) {
          u32x4 dd = *(const u32x4*)(src + e * 8);
          int mg = m0 + p * 64 + h * 32 + e * 8;
          int b = mg / 196, n = mg - b * 196;
          if (n <= 188) {
            u16* gp = outp + ((size_t)b * 12 + head) * HP + (size_t)cc * KP + n;
            *(u64*)gp       = ((const u64*)&dd)[0];
            *(u64*)(gp + 4) = ((const u64*)&dd)[1];
          } else {
            const u16* du = (const u16*)&dd;
#pragma unroll
            for (int ee = 0; ee < 8; ++ee) {
              int m2 = mg + ee, b2 = m2 / 196, n2 = m2 - b2 * 196;
              outp[((size_t)b2 * 12 + head) * HP + (size_t)cc * KP + n2] = du[ee];
            }
          }
        }
      }
      __syncthreads();
    }
  }
}

// ---------------- per-(b,h): kv & out on MFMA ; conv + z on VALU (r9 verbatim) ----------------
__global__ __launch_bounds__(256, 4) void attn_conv(
    const u16* __restrict__ q, const u16* kt, const u16* __restrict__ vt,
    u16* y, const float* __restrict__ dwc_w, const float* __restrict__ dwc_b)
{
  __shared__ __align__(16) char smem[30096];
  u16*   sKT = (u16*)smem;                   // also fmT after bar2
  u16*   sVT = (u16*)(smem + 13312);
  u16*   sKV = (u16*)(smem + 26624);         // kvT fp16 [d][40]
  float* sZ  = (float*)(smem + 29184);       // z[196]
  float* sKS = (float*)(smem + 29968);       // ksum[32]

  const int tid  = threadIdx.x;
  const int lane = tid & 63, wv = tid >> 6;
  const int r31 = lane & 31, hi = lane >> 5;
  const size_t bh = blockIdx.x;
  const u16* qh = q  + bh * PH;
  const u16* kh = kt + bh * HP;
  const u16* vh = vt + bh * HP;
  u16*       yh = y  + bh * HP;

  for (int i = tid; i < 832; i += 256) gload_lds16(kh + i * 8, smem + i * 16);
  for (int i = tid; i < 832; i += 256) gload_lds16(vh + i * 8, smem + 13312 + i * 16);
  __syncthreads();                                          // bar1

  if (wv == 0) {
    f32x16 kacc = {0,0,0,0,0,0,0,0,0,0,0,0,0,0,0,0};
#pragma unroll
    for (int kk = 0; kk < 13; ++kk) {
      hx8 a = *(const hx8*)(sKT + r31 * KP + kk * 16 + hi * 8);
      hx8 b = *(const hx8*)(sVT + r31 * KP + kk * 16 + hi * 8);
      kacc = __builtin_amdgcn_mfma_f32_32x32x16_f16(a, b, kacc, 0, 0, 0);
    }
#pragma unroll
    for (int r = 0; r < 16; ++r) {
      int cc = (r & 3) + 8 * (r >> 2) + 4 * hi;             // D row = c
      sKV[r31 * 40 + cc] = f2h(kacc[r]);                    // kvT[d=r31][c]
    }
  }

  {
    int c = tid >> 3, ns = tid & 7;
    float s = 0.f;
#pragma unroll
    for (int i = 0; i < 26; ++i) s += h2f(sKT[c * KP + ns * 26 + i]);
#pragma unroll
    for (int off = 1; off <= 4; off <<= 1) s += __shfl_xor(s, off);
    if (ns == 0) sKS[c] = s;
  }
  __syncthreads();                                          // bar2

  if (tid < 196) {
    float pz = 0.f;
#pragma unroll
    for (int g = 0; g < 4; ++g) {
      u32x4 qw = *(const u32x4*)(qh + (size_t)tid * 32 + g * 8);
#pragma unroll
      for (int j = 0; j < 4; ++j) {
        pz += h2f((u16)(qw[j] & 0xffffu)) * sKS[g * 8 + 2 * j]
            + h2f((u16)(qw[j] >> 16))     * sKS[g * 8 + 2 * j + 1];
      }
    }
    sZ[tid] = 1.f / (pz + 1e-6f);
  }

  u16* sFM = sKT;
  auto conv_unit = [&](int u) {
    int d = u & 31, py = u >> 5;
    float fm[14];
    float bv = dwc_b[d];
#pragma unroll
    for (int px = 0; px < 14; ++px) fm[px] = bv;
#pragma unroll
    for (int ky = 0; ky < 5; ++ky) {
      int yy = py + ky - 2;
      if (yy < 0 || yy >= 14) continue;
      float w[5];
#pragma unroll
      for (int t = 0; t < 5; ++t) w[t] = dwc_w[d * 25 + ky * 5 + t];
      float r[14];
      const u32* vrow = (const u32*)(sVT + d * KP + yy * 14);
#pragma unroll
      for (int x2 = 0; x2 < 7; ++x2) {
        u32 pr = vrow[x2];
        r[2 * x2]     = h2f((u16)(pr & 0xffffu));
        r[2 * x2 + 1] = h2f((u16)(pr >> 16));
      }
#pragma unroll
      for (int px = 0; px < 14; ++px) {
#pragma unroll
        for (int kx = 0; kx < 5; ++kx) {
          int xx = px + kx - 2;
          if (xx < 0 || xx > 13) continue;
          fm[px] += w[kx] * r[xx];
        }
      }
    }
#pragma unroll
    for (int px = 0; px < 14; ++px)
      sFM[d * KP + py * 14 + px] = f2h(fm[px]);
  };
  conv_unit(tid);
  if (tid >= 64) conv_unit(tid + 192);
  __syncthreads();                                          // bar3

#pragma unroll
  for (int rep = 0; rep < 2; ++rep) {
    int T = wv + rep * 4;
    if (T >= 7) break;
    const u16* qrow = qh + (size_t)(T * 32 + r31) * 32;
    f32x16 acc = {0,0,0,0,0,0,0,0,0,0,0,0,0,0,0,0};
#pragma unroll
    for (int s = 0; s < 2; ++s) {
      hx8 a = *(const hx8*)(qrow + hi * 8 + s * 16);
      hx8 b = *(const hx8*)(sKV + r31 * 40 + hi * 8 + s * 16);
      acc = __builtin_amdgcn_mfma_f32_32x32x16_f16(a, b, acc, 0, 0, 0);
    }
#pragma unroll
    for (int r = 0; r < 16; ++r) {
      int row = (r & 3) + 8 * (r >> 2) + 4 * hi;
      int n = T * 32 + row;
      if (n < 196) {
        float val = acc[r] * sZ[n] + h2f(sFM[r31 * KP + n]);
        yh[n * 32 + r31] = f2h(val);
      }
    }
  }
}

// ---------------- out = y @ proj_w^T + proj_b (fp16 MFMA) ----------------
__global__ __launch_bounds__(256, 4) void proj_gemm_f16(
    const u16* __restrict__ yf, const u16* __restrict__ wf,
    const float* __restrict__ bias, float* __restrict__ out)
{
  __shared__ __align__(16) char lds[2][16384];   // A 8K | B 8K
  const int tid  = threadIdx.x;
  const int lane = tid & 63, wv = tid >> 6;
  const int L  = ((int)blockIdx.x & 7) * 588 + ((int)blockIdx.x >> 3);  // 4704 = 8*588
  const int rt = L / 3, ct = L - rt * 3;
  const int m0 = rt * 128, t0 = ct * 128;

  const u16* spA[2];
  const u16* spB[2];
#pragma unroll
  for (int j = 0; j < 2; ++j) {
    int g = j * 256 + tid;
    int row = g >> 2, slot = g & 3;
    int c = slot ^ ((row >> 1) & 3);
    int m = m0 + row;
    int b = m / 196, n = m - b * 196;
    spA[j] = yf + (size_t)b * (12 * HP) + (size_t)n * 32 + c * 8;  // += HP per head
    spB[j] = wf + (size_t)(t0 + row) * NC + c * 8;
  }

  auto stage = [&](char* buf) {
#pragma unroll
    for (int j = 0; j < 2; ++j) {
      gload_lds16(spA[j], buf + (j * 256 + tid) * 16);
      spA[j] += HP;
      gload_lds16(spB[j], buf + 8192 + (j * 256 + tid) * 16);
      spB[j] += 32;
    }
  };

  const int wm = (wv & 1) * 64, wn = (wv >> 1) * 64;
  const int l15 = lane & 15, l4 = lane >> 4;
  const int sl = l4 ^ ((l15 >> 1) & 3);
  int aoff[4], boff[4];
#pragma unroll
  for (int i = 0; i < 4; ++i) {
    aoff[i] = (wm + i * 16 + l15) * 64 + sl * 16;
    boff[i] = 8192 + (wn + i * 16 + l15) * 64 + sl * 16;
  }

  f4 acc[4][4];
  const f4 fz = {0.f, 0.f, 0.f, 0.f};
#pragma unroll
  for (int i = 0; i < 4; ++i)
#pragma unroll
    for (int j = 0; j < 4; ++j) acc[i][j] = fz;

  stage(lds[0]);
  for (int kt = 0; kt < 12; ++kt) {
    __syncthreads();
    if (kt < 11) stage(lds[(kt + 1) & 1]);
    char* buf = lds[kt & 1];
    hx8 af[4], bf4[4];
#pragma unroll
    for (int i = 0; i < 4; ++i) {
      af[i]  = *(const hx8*)(buf + aoff[i]);
      bf4[i] = *(const hx8*)(buf + boff[i]);
    }
#pragma unroll
    for (int mi = 0; mi < 4; ++mi)
#pragma unroll
      for (int ni = 0; ni < 4; ++ni)
        acc[mi][ni] = __builtin_amdgcn_mfma_f32_16x16x32_f16(af[mi], bf4[ni], acc[mi][ni], 0, 0, 0);
  }

  float biasv[4];
#pragma unroll
  for (int ni = 0; ni < 4; ++ni) biasv[ni] = bias[t0 + wn + ni * 16 + l15];
#pragma unroll
  for (int mi = 0; mi < 4; ++mi) {
#pragma unroll
    for (int rr = 0; rr < 4; ++rr) {
      int m = m0 + wm + mi * 16 + l4 * 4 + rr;
      size_t ob = (size_t)m * 384 + t0 + wn;
#pragma unroll
      for (int ni = 0; ni < 4; ++ni)
        out[ob + ni * 16 + l15] = acc[mi][ni][rr] + biasv[ni];
    }
  }
}

// ---------------- launcher ----------------
extern "C" void kernel_launch(void* const* d_in, const int* in_sizes, int n_in,
                              void* d_out, int out_size, void* d_ws, size_t ws_size,
                              hipStream_t stream)
{
  const float* x      = (const float*)d_in[0];
  const float* qkv_w  = (const float*)d_in[1];
  const float* qkv_b  = (const float*)d_in[2];
  const float* proj_w = (const float*)d_in[3];
  const float* proj_b = (const float*)d_in[4];
  const float* dwc_w  = (const float*)d_in[5];
  const float* dwc_b  = (const float*)d_in[6];
  const float* pos    = (const float*)d_in[7];
  float* out = (float*)d_out;
  char* ws = (char*)d_ws;

  u16* qb  = (u16*)(ws + OFF_Q);     // q fp16 [bh][n][32]
  u16* kb  = (u16*)(ws + OFF_K);     // kT fp16 [bh][c][208]
  u16* vb  = (u16*)(ws + OFF_V);     // vT fp16 [bh][d][208]
  u16* wqf = (u16*)(ws + OFF_WQF);
  u16* wpf = (u16*)(ws + OFF_WPF);
  u16* xf  = (u16*)(ws + OFF_XF);
  u16* yb  = (u16*)(ws + OFF_K);     // y fp16 [bh][n][32] (head stride HP), overlays kT

  split_weights<<<1728, 256, 0, stream>>>(qkv_w, proj_w, wqf, wpf, kb, vb);
  cvt_x_f16<<<37632, 256, 0, stream>>>(x, xf);
  qkv_gemm_f16<<<14112, 256, 0, stream>>>(xf, wqf, qkv_b, pos, qb, kb, vb);
  attn_conv<<<12288, 256, 0, stream>>>(qb, kb, vb, yb, dwc_w, dwc_b);
  proj_gemm_f16<<<4704, 256, 0, stream>>>(yb, wpf, proj_b, out);
}